// Round 5
// baseline (519.602 us; speedup 1.0000x reference)
//
#include <hip/hip_runtime.h>
#include <math.h>

#define N_NODES 50000
#define N_EDGES 800000
#define N_GRAPHS 16
#define NODE_F 128
#define HID 64
#define OUT_F 128
#define HEADS 3
#define NEG 0.2f
#define FEAT (HEADS*HID)  // 192

typedef float f32x4 __attribute__((ext_vector_type(4)));
typedef short bf16x8 __attribute__((ext_vector_type(8)));

__device__ __forceinline__ ushort f2bf(float x) {
  union { float f; unsigned u; } v; v.f = x;
  unsigned r = v.u + 0x7fff + ((v.u >> 16) & 1);  // round-to-nearest-even
  return (ushort)(r >> 16);
}
__device__ __forceinline__ float bf2f(ushort x) {
  union { unsigned u; float f; } v; v.u = ((unsigned)x) << 16;
  return v.f;
}

// ---------------- K0: feat = h @ fc_w.T via MFMA bf16; el/er in epilogue ----------------
__global__ __launch_bounds__(256) void k0_mfma(
    const float* __restrict__ h, const float* __restrict__ fc_w,
    const float* __restrict__ attn_l, const float* __restrict__ attn_r,
    ushort* __restrict__ feat, float* __restrict__ el, float* __restrict__ er)
{
  __shared__ ushort A[64][136];   // bf16, 272 B row stride
  __shared__ ushort Bs[192][40];  // bf16 K-slice, 80 B row stride
  const int tid = threadIdx.x;
  const int n0 = blockIdx.x * 64;

  for (int i = tid; i < 64 * 32; i += 256) {
    int r = i >> 5, c4 = i & 31;
    if (n0 + r < N_NODES) {
      float4 v = *(const float4*)(h + (size_t)(n0 + r) * NODE_F + c4 * 4);
      unsigned lo = f2bf(v.x) | ((unsigned)f2bf(v.y) << 16);
      unsigned hi = f2bf(v.z) | ((unsigned)f2bf(v.w) << 16);
      *(uint2*)&A[r][c4 * 4] = make_uint2(lo, hi);
    }
  }

  const int lane = tid & 63, wv = tid >> 6;
  const int m = lane & 15, kq = lane >> 4;

  f32x4 acc[12];
#pragma unroll
  for (int t = 0; t < 12; t++) acc[t] = (f32x4){0.f, 0.f, 0.f, 0.f};

  for (int kk = 0; kk < 4; kk++) {
    __syncthreads();
    for (int i = tid; i < 192 * 8; i += 256) {
      int r = i >> 3, c4 = i & 7;
      float4 v = *(const float4*)(fc_w + (size_t)r * NODE_F + kk * 32 + c4 * 4);
      unsigned lo = f2bf(v.x) | ((unsigned)f2bf(v.y) << 16);
      unsigned hi = f2bf(v.z) | ((unsigned)f2bf(v.w) << 16);
      *(uint2*)&Bs[r][c4 * 4] = make_uint2(lo, hi);
    }
    __syncthreads();
    bf16x8 af = *(const bf16x8*)&A[wv * 16 + m][kk * 32 + kq * 8];
#pragma unroll
    for (int t = 0; t < 12; t++) {
      bf16x8 bf = *(const bf16x8*)&Bs[t * 16 + m][kq * 8];
      acc[t] = __builtin_amdgcn_mfma_f32_16x16x32_bf16(af, bf, acc[t], 0, 0, 0);
    }
  }

  const int rbase = n0 + wv * 16 + kq * 4;
#pragma unroll
  for (int t = 0; t < 12; t++) {
#pragma unroll
    for (int reg = 0; reg < 4; reg++) {
      int n = rbase + reg;
      if (n < N_NODES) feat[(size_t)n * FEAT + t * 16 + m] = f2bf(acc[t][reg]);
    }
  }

#pragma unroll
  for (int hh = 0; hh < HEADS; hh++) {
    float elv[4] = {0.f, 0.f, 0.f, 0.f};
    float erv[4] = {0.f, 0.f, 0.f, 0.f};
#pragma unroll
    for (int tt = 0; tt < 4; tt++) {
      int t = hh * 4 + tt;
      float al = attn_l[hh * HID + tt * 16 + m];
      float ar = attn_r[hh * HID + tt * 16 + m];
#pragma unroll
      for (int reg = 0; reg < 4; reg++) {
        elv[reg] = fmaf(acc[t][reg], al, elv[reg]);
        erv[reg] = fmaf(acc[t][reg], ar, erv[reg]);
      }
    }
#pragma unroll
    for (int reg = 0; reg < 4; reg++) {
#pragma unroll
      for (int off = 1; off < 16; off <<= 1) {
        elv[reg] += __shfl_xor(elv[reg], off, 64);
        erv[reg] += __shfl_xor(erv[reg], off, 64);
      }
      int n = rbase + reg;
      if (m == 0 && n < N_NODES) {
        el[(size_t)n * 4 + hh] = elv[reg];
        er[(size_t)n * 4 + hh] = erv[reg];
      }
    }
  }
}

// ---------------- K1: per-edge weights + degree histogram + denominator atomics ----------------
__global__ __launch_bounds__(256) void k1_edge(
    const int* __restrict__ src, const int* __restrict__ dst,
    const float* __restrict__ el4, const float* __restrict__ er4,
    int* __restrict__ deg, float* __restrict__ sum4, float4* __restrict__ we)
{
  int e = blockIdx.x * 256 + threadIdx.x;  // grid exact: E/256
  int s = src[e], d = dst[e];
  atomicAdd(&deg[d], 1);
  float4 elv = ((const float4*)el4)[s];
  float4 erv = ((const float4*)er4)[d];
  float e0 = elv.x + erv.x; e0 = e0 > 0.f ? e0 : NEG * e0;
  float e1 = elv.y + erv.y; e1 = e1 > 0.f ? e1 : NEG * e1;
  float e2 = elv.z + erv.z; e2 = e2 > 0.f ? e2 : NEG * e2;
  float w0 = __expf(e0), w1 = __expf(e1), w2 = __expf(e2);
  float4 r; r.x = w0; r.y = w1; r.z = w2; r.w = __int_as_float(s);
  we[e] = r;
  atomicAdd(&sum4[d * 4 + 0], w0);
  atomicAdd(&sum4[d * 4 + 1], w1);
  atomicAdd(&sum4[d * 4 + 2], w2);
}

// ---------------- K2: coalesced 3-stage exclusive scan ----------------
#define SCAN_T 1024
#define SCAN_NB 49  // ceil(50000/1024)

__global__ __launch_bounds__(SCAN_T) void k2a_blocksum(
    const int* __restrict__ deg, int* __restrict__ bsum)
{
  const int tid = threadIdx.x;
  int idx = blockIdx.x * SCAN_T + tid;
  int v = (idx < N_NODES) ? deg[idx] : 0;
#pragma unroll
  for (int off = 32; off; off >>= 1) v += __shfl_xor(v, off, 64);
  __shared__ int ws_[16];
  if ((tid & 63) == 0) ws_[tid >> 6] = v;
  __syncthreads();
  if (tid == 0) {
    int s = 0;
    for (int i = 0; i < 16; i++) s += ws_[i];
    bsum[blockIdx.x] = s;
  }
}

__global__ __launch_bounds__(64) void k2b_scanb(
    const int* __restrict__ bsum, int* __restrict__ boff, int* __restrict__ offs)
{
  const int lane = threadIdx.x;
  int v = (lane < SCAN_NB) ? bsum[lane] : 0;
  int s = v;
#pragma unroll
  for (int off = 1; off < 64; off <<= 1) {
    int t = __shfl_up(s, off, 64);
    if (lane >= off) s += t;
  }
  if (lane < SCAN_NB) boff[lane] = s - v;
  if (lane == SCAN_NB - 1) offs[N_NODES] = s;
}

__global__ __launch_bounds__(SCAN_T) void k2c_apply(
    const int* __restrict__ deg, const int* __restrict__ boff,
    int* __restrict__ offs, int* __restrict__ cursor)
{
  __shared__ int lds[SCAN_T];
  const int tid = threadIdx.x;
  const int idx = blockIdx.x * SCAN_T + tid;
  int v = (idx < N_NODES) ? deg[idx] : 0;
  int s = v;
  lds[tid] = s;
  __syncthreads();
  for (int off = 1; off < SCAN_T; off <<= 1) {
    int t = (tid >= off) ? lds[tid - off] : 0;
    __syncthreads();
    s += t;
    lds[tid] = s;
    __syncthreads();
  }
  int excl = s - v + boff[blockIdx.x];
  if (idx < N_NODES) {
    offs[idx] = excl;
    cursor[idx] = excl;
  }
}

// ---------------- K3: scatter {w0,w1,w2,src} records into CSR-by-dst ----------------
__global__ __launch_bounds__(256) void k3_scatter(
    const int* __restrict__ dst, const float4* __restrict__ we,
    int* __restrict__ cursor, float4* __restrict__ csr_w) {
  int e = blockIdx.x * 256 + threadIdx.x;
  int d = dst[e];
  float4 wv = we[e];
  int pos = atomicAdd(&cursor[d], 1);
  csr_w[pos] = wv;
}

// ---------------- K4: wave per (node, head): weighted gather-aggregate ----------------
__global__ __launch_bounds__(256) void k4_agg(
    const int* __restrict__ offs, const float4* __restrict__ csr_w,
    const float* __restrict__ sum4, const ushort* __restrict__ feat,
    const float* __restrict__ bias, float* __restrict__ h_d)
{
  const int wid = blockIdx.x * 4 + (threadIdx.x >> 6);  // < 3*N
  const int lane = threadIdx.x & 63;
  const int hh = wid / N_NODES;
  const int n = wid - hh * N_NODES;
  const int lo = offs[n], hi = offs[n + 1];
  const float sm = sum4[n * 4 + hh];
  const float inv = sm > 0.f ? 1.f / sm : 0.f;

  float acc = 0.f;
  for (int base = lo; base < hi; base += 64) {
    const int cnt = min(64, hi - base);
    float w = 0.f; int sj = 0;
    if (lane < cnt) {
      float4 c = csr_w[base + lane];
      sj = __float_as_int(c.w);
      w = (hh == 0) ? c.x : ((hh == 1) ? c.y : c.z);
    }
    for (int j = 0; j < cnt; j++) {
      float b = __shfl(w, j, 64);
      int ss = __shfl(sj, j, 64);
      acc = fmaf(b, bf2f(feat[(size_t)ss * FEAT + hh * HID + lane]), acc);
    }
  }
  float val = fmaf(acc, inv, bias[hh * HID + lane]) * (1.f / 3.f);
  atomicAdd(&h_d[(size_t)n * HID + lane], val);
}

// ---------------- K5: per-graph SUM pooling, grid-stride partials ----------------
#define K5_NPB 128
__global__ __launch_bounds__(256) void k5a_partial(
    const int* __restrict__ graph_id, const float* __restrict__ h_d,
    float* __restrict__ pooled_sum)
{
  const int wave = threadIdx.x >> 6, lane = threadIdx.x & 63;
  const int n0 = blockIdx.x * K5_NPB;
  const int n1 = min(n0 + K5_NPB, N_NODES);
  float acc = 0.f;
  int cur_g = -1;
  for (int i = n0 + wave; i < n1; i += 4) {
    int g = graph_id[i];
    if (g != cur_g) {
      if (cur_g >= 0) atomicAdd(&pooled_sum[cur_g * HID + lane], acc);
      acc = 0.f; cur_g = g;
    }
    acc += h_d[(size_t)i * HID + lane];
  }
  if (cur_g >= 0) atomicAdd(&pooled_sum[cur_g * HID + lane], acc);
}

// ---------------- K6: counts + mean, z @ lin1.T, concat, lin2, sigmoid ----------------
__global__ __launch_bounds__(256) void k6_final(
    const int* __restrict__ graph_id, const float* __restrict__ pooled_sum,
    const float* __restrict__ z,
    const float* __restrict__ lin1_w, const float* __restrict__ lin1_b,
    const float* __restrict__ lin2_w, const float* __restrict__ lin2_b,
    float* __restrict__ out)
{
  __shared__ float cat[N_GRAPHS][2 * HID];
  __shared__ float inv_cnt[N_GRAPHS];
  const int tid = threadIdx.x;
  if (tid < N_GRAPHS) {
    int g = tid;
    int lo, hi;
    { int l = 0, r = N_NODES; while (l < r) { int m = (l + r) >> 1; if (graph_id[m] < g) l = m + 1; else r = m; } lo = l; }
    { int l = 0, r = N_NODES; while (l < r) { int m = (l + r) >> 1; if (graph_id[m] < g + 1) l = m + 1; else r = m; } hi = l; }
    int cnt = hi - lo;
    inv_cnt[g] = 1.f / (float)(cnt > 0 ? cnt : 1);
  }
  __syncthreads();
  for (int i = tid; i < N_GRAPHS * HID; i += 256) {
    cat[i >> 6][i & 63] = pooled_sum[i] * inv_cnt[i >> 6];
  }
  for (int i = tid; i < N_GRAPHS * HID; i += 256) {
    int g = i >> 6, j = i & 63;
    float s = lin1_b[j];
    const float* zr = z + g * OUT_F;
    const float* wr = lin1_w + j * OUT_F;
    for (int k = 0; k < OUT_F; k += 4) {
      float4 zv = *(const float4*)(zr + k);
      float4 wv = *(const float4*)(wr + k);
      s = fmaf(zv.x, wv.x, fmaf(zv.y, wv.y, fmaf(zv.z, wv.z, fmaf(zv.w, wv.w, s))));
    }
    cat[g][HID + j] = s;
  }
  __syncthreads();
  if (tid < N_GRAPHS) {
    float s = lin2_b[0];
    for (int i = 0; i < 2 * HID; i++) s += cat[tid][i] * lin2_w[i];
    out[tid] = 1.f / (1.f + __expf(-s));
  }
}

extern "C" void kernel_launch(void* const* d_in, const int* in_sizes, int n_in,
                              void* d_out, int out_size, void* d_ws, size_t ws_size,
                              hipStream_t stream) {
  (void)in_sizes; (void)n_in; (void)out_size; (void)ws_size;
  const float* h      = (const float*)d_in[0];
  const float* z      = (const float*)d_in[1];
  const int*   src    = (const int*)d_in[2];
  const int*   dst    = (const int*)d_in[3];
  const int*   gid    = (const int*)d_in[4];
  const float* fc_w   = (const float*)d_in[5];
  const float* attn_l = (const float*)d_in[6];
  const float* attn_r = (const float*)d_in[7];
  const float* bias   = (const float*)d_in[8];
  const float* lin1_w = (const float*)d_in[9];
  const float* lin1_b = (const float*)d_in[10];
  const float* lin2_w = (const float*)d_in[11];
  const float* lin2_b = (const float*)d_in[12];
  float* out = (float*)d_out;

  // workspace layout (~61 MB), float4 arrays first for 16-B alignment
  float4* csr_w     = (float4*)d_ws;                         // E  (12.8 MB)
  float4* we        = csr_w + N_EDGES;                       // E  (12.8 MB)
  ushort* feat      = (ushort*)(we + N_EDGES);               // N*192 bf16 (19.2 MB)
  float* el         = (float*)(feat + (size_t)N_NODES * FEAT);
  float* er         = el + (size_t)N_NODES * 4;              // N*4
  // --- zeroed region: h_d, pooled_sum, sum4, deg (contiguous, one memset) ---
  float* h_d        = er + (size_t)N_NODES * 4;              // N*64 (12.8 MB)
  float* pooled_sum = h_d + (size_t)N_NODES * HID;           // 16*64
  float* sum4       = pooled_sum + N_GRAPHS * HID;           // N*4
  int* deg          = (int*)(sum4 + (size_t)N_NODES * 4);    // N+1
  // --- end zeroed region ---
  int* offs         = deg + (N_NODES + 1);                   // N+1
  int* cursor       = offs + (N_NODES + 1);                  // N
  int* bsum         = cursor + N_NODES;                      // 49
  int* boff         = bsum + SCAN_NB;                        // 49

  size_t zero_bytes = (size_t)N_NODES * HID * 4 + N_GRAPHS * HID * 4
                    + (size_t)N_NODES * 4 * 4 + (N_NODES + 1) * 4;
  hipMemsetAsync(h_d, 0, zero_bytes, stream);

  k0_mfma<<<(N_NODES + 63) / 64, 256, 0, stream>>>(h, fc_w, attn_l, attn_r, feat, el, er);
  k1_edge<<<N_EDGES / 256, 256, 0, stream>>>(src, dst, el, er, deg, sum4, we);
  k2a_blocksum<<<SCAN_NB, SCAN_T, 0, stream>>>(deg, bsum);
  k2b_scanb<<<1, 64, 0, stream>>>(bsum, boff, offs);
  k2c_apply<<<SCAN_NB, SCAN_T, 0, stream>>>(deg, boff, offs, cursor);
  k3_scatter<<<N_EDGES / 256, 256, 0, stream>>>(dst, we, cursor, csr_w);
  k4_agg<<<(3 * N_NODES) / 4, 256, 0, stream>>>(offs, csr_w, sum4, feat, bias, h_d);
  k5a_partial<<<(N_NODES + K5_NPB - 1) / K5_NPB, 256, 0, stream>>>(gid, h_d, pooled_sum);
  k6_final<<<1, 256, 0, stream>>>(gid, pooled_sum, z, lin1_w, lin1_b, lin2_w, lin2_b, out);
}

// Round 6
// 315.917 us; speedup vs baseline: 1.6447x; 1.6447x over previous
//
#include <hip/hip_runtime.h>
#include <math.h>

#define N_NODES 50000
#define N_EDGES 800000
#define N_GRAPHS 16
#define NODE_F 128
#define HID 64
#define OUT_F 128
#define HEADS 3
#define NEG 0.2f
#define FEAT (HEADS*HID)  // 192

typedef float f32x4 __attribute__((ext_vector_type(4)));
typedef short bf16x8 __attribute__((ext_vector_type(8)));

__device__ __forceinline__ ushort f2bf(float x) {
  union { float f; unsigned u; } v; v.f = x;
  unsigned r = v.u + 0x7fff + ((v.u >> 16) & 1);  // round-to-nearest-even
  return (ushort)(r >> 16);
}
__device__ __forceinline__ float bf2f(ushort x) {
  union { unsigned u; float f; } v; v.u = ((unsigned)x) << 16;
  return v.f;
}

// ---------------- K0: feat = h @ fc_w.T via MFMA bf16; el/er in epilogue ----------------
__global__ __launch_bounds__(256) void k0_mfma(
    const float* __restrict__ h, const float* __restrict__ fc_w,
    const float* __restrict__ attn_l, const float* __restrict__ attn_r,
    ushort* __restrict__ feat, float* __restrict__ el, float* __restrict__ er)
{
  __shared__ ushort A[64][136];   // bf16, 272 B row stride
  __shared__ ushort Bs[192][40];  // bf16 K-slice, 80 B row stride
  const int tid = threadIdx.x;
  const int n0 = blockIdx.x * 64;

  for (int i = tid; i < 64 * 32; i += 256) {
    int r = i >> 5, c4 = i & 31;
    if (n0 + r < N_NODES) {
      float4 v = *(const float4*)(h + (size_t)(n0 + r) * NODE_F + c4 * 4);
      unsigned lo = f2bf(v.x) | ((unsigned)f2bf(v.y) << 16);
      unsigned hi = f2bf(v.z) | ((unsigned)f2bf(v.w) << 16);
      *(uint2*)&A[r][c4 * 4] = make_uint2(lo, hi);
    }
  }

  const int lane = tid & 63, wv = tid >> 6;
  const int m = lane & 15, kq = lane >> 4;

  f32x4 acc[12];
#pragma unroll
  for (int t = 0; t < 12; t++) acc[t] = (f32x4){0.f, 0.f, 0.f, 0.f};

  for (int kk = 0; kk < 4; kk++) {
    __syncthreads();
    for (int i = tid; i < 192 * 8; i += 256) {
      int r = i >> 3, c4 = i & 7;
      float4 v = *(const float4*)(fc_w + (size_t)r * NODE_F + kk * 32 + c4 * 4);
      unsigned lo = f2bf(v.x) | ((unsigned)f2bf(v.y) << 16);
      unsigned hi = f2bf(v.z) | ((unsigned)f2bf(v.w) << 16);
      *(uint2*)&Bs[r][c4 * 4] = make_uint2(lo, hi);
    }
    __syncthreads();
    bf16x8 af = *(const bf16x8*)&A[wv * 16 + m][kk * 32 + kq * 8];
#pragma unroll
    for (int t = 0; t < 12; t++) {
      bf16x8 bf = *(const bf16x8*)&Bs[t * 16 + m][kq * 8];
      acc[t] = __builtin_amdgcn_mfma_f32_16x16x32_bf16(af, bf, acc[t], 0, 0, 0);
    }
  }

  const int rbase = n0 + wv * 16 + kq * 4;
#pragma unroll
  for (int t = 0; t < 12; t++) {
#pragma unroll
    for (int reg = 0; reg < 4; reg++) {
      int n = rbase + reg;
      if (n < N_NODES) feat[(size_t)n * FEAT + t * 16 + m] = f2bf(acc[t][reg]);
    }
  }

#pragma unroll
  for (int hh = 0; hh < HEADS; hh++) {
    float elv[4] = {0.f, 0.f, 0.f, 0.f};
    float erv[4] = {0.f, 0.f, 0.f, 0.f};
#pragma unroll
    for (int tt = 0; tt < 4; tt++) {
      int t = hh * 4 + tt;
      float al = attn_l[hh * HID + tt * 16 + m];
      float ar = attn_r[hh * HID + tt * 16 + m];
#pragma unroll
      for (int reg = 0; reg < 4; reg++) {
        elv[reg] = fmaf(acc[t][reg], al, elv[reg]);
        erv[reg] = fmaf(acc[t][reg], ar, erv[reg]);
      }
    }
#pragma unroll
    for (int reg = 0; reg < 4; reg++) {
#pragma unroll
      for (int off = 1; off < 16; off <<= 1) {
        elv[reg] += __shfl_xor(elv[reg], off, 64);
        erv[reg] += __shfl_xor(erv[reg], off, 64);
      }
      int n = rbase + reg;
      if (m == 0 && n < N_NODES) {
        el[(size_t)n * 4 + hh] = elv[reg];
        er[(size_t)n * 4 + hh] = erv[reg];
      }
    }
  }
}

// ---------------- K1: in-degree histogram (int atomics — proven cheap) ----------------
__global__ void k1_hist(const int* __restrict__ dst, int* __restrict__ deg) {
  int e = blockIdx.x * 256 + threadIdx.x;
  atomicAdd(&deg[dst[e]], 1);
}

// ---------------- K2: coalesced 3-stage exclusive scan ----------------
#define SCAN_T 1024
#define SCAN_NB 49  // ceil(50000/1024)

__global__ __launch_bounds__(SCAN_T) void k2a_blocksum(
    const int* __restrict__ deg, int* __restrict__ bsum)
{
  const int tid = threadIdx.x;
  int idx = blockIdx.x * SCAN_T + tid;
  int v = (idx < N_NODES) ? deg[idx] : 0;
#pragma unroll
  for (int off = 32; off; off >>= 1) v += __shfl_xor(v, off, 64);
  __shared__ int ws_[16];
  if ((tid & 63) == 0) ws_[tid >> 6] = v;
  __syncthreads();
  if (tid == 0) {
    int s = 0;
    for (int i = 0; i < 16; i++) s += ws_[i];
    bsum[blockIdx.x] = s;
  }
}

__global__ __launch_bounds__(64) void k2b_scanb(
    const int* __restrict__ bsum, int* __restrict__ boff, int* __restrict__ offs)
{
  const int lane = threadIdx.x;
  int v = (lane < SCAN_NB) ? bsum[lane] : 0;
  int s = v;
#pragma unroll
  for (int off = 1; off < 64; off <<= 1) {
    int t = __shfl_up(s, off, 64);
    if (lane >= off) s += t;
  }
  if (lane < SCAN_NB) boff[lane] = s - v;
  if (lane == SCAN_NB - 1) offs[N_NODES] = s;
}

__global__ __launch_bounds__(SCAN_T) void k2c_apply(
    const int* __restrict__ deg, const int* __restrict__ boff,
    int* __restrict__ offs, int* __restrict__ cursor)
{
  __shared__ int lds[SCAN_T];
  const int tid = threadIdx.x;
  const int idx = blockIdx.x * SCAN_T + tid;
  int v = (idx < N_NODES) ? deg[idx] : 0;
  int s = v;
  lds[tid] = s;
  __syncthreads();
  for (int off = 1; off < SCAN_T; off <<= 1) {
    int t = (tid >= off) ? lds[tid - off] : 0;
    __syncthreads();
    s += t;
    lds[tid] = s;
    __syncthreads();
  }
  int excl = s - v + boff[blockIdx.x];
  if (idx < N_NODES) {
    offs[idx] = excl;
    cursor[idx] = excl;
  }
}

// ---------------- K3: fused edge-weight compute + scatter {w0,w1,w2,src} into CSR ----------------
__global__ __launch_bounds__(256) void k3_edge(
    const int* __restrict__ src, const int* __restrict__ dst,
    const float* __restrict__ el4, const float* __restrict__ er4,
    int* __restrict__ cursor, float4* __restrict__ csr_w)
{
  int e = blockIdx.x * 256 + threadIdx.x;  // grid exact E/256
  int s = src[e], d = dst[e];
  int pos = atomicAdd(&cursor[d], 1);
  float4 elv = ((const float4*)el4)[s];
  float4 erv = ((const float4*)er4)[d];
  float e0 = elv.x + erv.x; e0 = e0 > 0.f ? e0 : NEG * e0;
  float e1 = elv.y + erv.y; e1 = e1 > 0.f ? e1 : NEG * e1;
  float e2 = elv.z + erv.z; e2 = e2 > 0.f ? e2 : NEG * e2;
  float4 r;
  r.x = __expf(e0); r.y = __expf(e1); r.z = __expf(e2);
  r.w = __int_as_float(s);
  csr_w[pos] = r;
}

// ---------------- K4: wave per (node, head); single sweep (norm is linear) ----------------
__global__ __launch_bounds__(256) void k4_agg(
    const int* __restrict__ offs, const float4* __restrict__ csr_w,
    const ushort* __restrict__ feat, const float* __restrict__ bias,
    ushort* __restrict__ h_d3)
{
  const int wid = blockIdx.x * 4 + (threadIdx.x >> 6);  // < 3*N exactly
  const int lane = threadIdx.x & 63;
  const int hh = wid / N_NODES;
  const int n = wid - hh * N_NODES;
  const int lo = offs[n], hi = offs[n + 1];
  const size_t fof = (size_t)hh * HID + lane;

  float s = 0.f;    // denominator partial (lane-own)
  float acc = 0.f;  // unnormalized numerator for dim `lane`
  for (int base = lo; base < hi; base += 64) {
    const int cnt = min(64, hi - base);
    float w = 0.f; int sj = 0;
    if (lane < cnt) {
      float4 c = csr_w[base + lane];
      sj = __float_as_int(c.w);
      w = (hh == 0) ? c.x : ((hh == 1) ? c.y : c.z);
      s += w;
    }
    int j = 0;
    for (; j + 4 <= cnt; j += 4) {  // 4 independent gathers in flight
      float b0 = __shfl(w, j, 64),     b1 = __shfl(w, j + 1, 64);
      float b2 = __shfl(w, j + 2, 64), b3 = __shfl(w, j + 3, 64);
      int t0 = __shfl(sj, j, 64),     t1 = __shfl(sj, j + 1, 64);
      int t2 = __shfl(sj, j + 2, 64), t3 = __shfl(sj, j + 3, 64);
      float f0 = bf2f(feat[(size_t)t0 * FEAT + fof]);
      float f1 = bf2f(feat[(size_t)t1 * FEAT + fof]);
      float f2 = bf2f(feat[(size_t)t2 * FEAT + fof]);
      float f3 = bf2f(feat[(size_t)t3 * FEAT + fof]);
      acc = fmaf(b0, f0, acc);
      acc = fmaf(b1, f1, acc);
      acc = fmaf(b2, f2, acc);
      acc = fmaf(b3, f3, acc);
    }
    for (; j < cnt; j++) {
      float b = __shfl(w, j, 64);
      int tt = __shfl(sj, j, 64);
      acc = fmaf(b, bf2f(feat[(size_t)tt * FEAT + fof]), acc);
    }
  }
#pragma unroll
  for (int off = 32; off; off >>= 1) s += __shfl_xor(s, off, 64);
  const float inv = s > 0.f ? 1.f / s : 0.f;
  float val = fmaf(acc * inv, 1.f, bias[hh * HID + lane]) * (1.f / 3.f);
  h_d3[(size_t)hh * N_NODES * HID + (size_t)n * HID + lane] = f2bf(val);
}

// ---------------- K5: sum 3 heads + per-graph pooling partials ----------------
#define K5_NPB 128
__global__ __launch_bounds__(256) void k5a_partial(
    const int* __restrict__ graph_id, const ushort* __restrict__ h_d3,
    float* __restrict__ pooled_sum)
{
  const int wave = threadIdx.x >> 6, lane = threadIdx.x & 63;
  const int n0 = blockIdx.x * K5_NPB;
  const int n1 = min(n0 + K5_NPB, N_NODES);
  const size_t HP = (size_t)N_NODES * HID;
  float acc = 0.f;
  int cur_g = -1;
  for (int i = n0 + wave; i < n1; i += 4) {
    int g = graph_id[i];
    if (g != cur_g) {
      if (cur_g >= 0) atomicAdd(&pooled_sum[cur_g * HID + lane], acc);
      acc = 0.f; cur_g = g;
    }
    size_t o = (size_t)i * HID + lane;
    acc += bf2f(h_d3[o]) + bf2f(h_d3[HP + o]) + bf2f(h_d3[2 * HP + o]);
  }
  if (cur_g >= 0) atomicAdd(&pooled_sum[cur_g * HID + lane], acc);
}

// ---------------- K6: counts + mean, z @ lin1.T, concat, lin2, sigmoid ----------------
__global__ __launch_bounds__(256) void k6_final(
    const int* __restrict__ graph_id, const float* __restrict__ pooled_sum,
    const float* __restrict__ z,
    const float* __restrict__ lin1_w, const float* __restrict__ lin1_b,
    const float* __restrict__ lin2_w, const float* __restrict__ lin2_b,
    float* __restrict__ out)
{
  __shared__ float cat[N_GRAPHS][2 * HID];
  __shared__ float inv_cnt[N_GRAPHS];
  const int tid = threadIdx.x;
  if (tid < N_GRAPHS) {
    int g = tid;
    int lo, hi;
    { int l = 0, r = N_NODES; while (l < r) { int m = (l + r) >> 1; if (graph_id[m] < g) l = m + 1; else r = m; } lo = l; }
    { int l = 0, r = N_NODES; while (l < r) { int m = (l + r) >> 1; if (graph_id[m] < g + 1) l = m + 1; else r = m; } hi = l; }
    int cnt = hi - lo;
    inv_cnt[g] = 1.f / (float)(cnt > 0 ? cnt : 1);
  }
  __syncthreads();
  for (int i = tid; i < N_GRAPHS * HID; i += 256) {
    cat[i >> 6][i & 63] = pooled_sum[i] * inv_cnt[i >> 6];
  }
  for (int i = tid; i < N_GRAPHS * HID; i += 256) {
    int g = i >> 6, j = i & 63;
    float s = lin1_b[j];
    const float* zr = z + g * OUT_F;
    const float* wr = lin1_w + j * OUT_F;
    for (int k = 0; k < OUT_F; k += 4) {
      float4 zv = *(const float4*)(zr + k);
      float4 wv = *(const float4*)(wr + k);
      s = fmaf(zv.x, wv.x, fmaf(zv.y, wv.y, fmaf(zv.z, wv.z, fmaf(zv.w, wv.w, s))));
    }
    cat[g][HID + j] = s;
  }
  __syncthreads();
  if (tid < N_GRAPHS) {
    float s = lin2_b[0];
    for (int i = 0; i < 2 * HID; i++) s += cat[tid][i] * lin2_w[i];
    out[tid] = 1.f / (1.f + __expf(-s));
  }
}

extern "C" void kernel_launch(void* const* d_in, const int* in_sizes, int n_in,
                              void* d_out, int out_size, void* d_ws, size_t ws_size,
                              hipStream_t stream) {
  (void)in_sizes; (void)n_in; (void)out_size; (void)ws_size;
  const float* h      = (const float*)d_in[0];
  const float* z      = (const float*)d_in[1];
  const int*   src    = (const int*)d_in[2];
  const int*   dst    = (const int*)d_in[3];
  const int*   gid    = (const int*)d_in[4];
  const float* fc_w   = (const float*)d_in[5];
  const float* attn_l = (const float*)d_in[6];
  const float* attn_r = (const float*)d_in[7];
  const float* bias   = (const float*)d_in[8];
  const float* lin1_w = (const float*)d_in[9];
  const float* lin1_b = (const float*)d_in[10];
  const float* lin2_w = (const float*)d_in[11];
  const float* lin2_b = (const float*)d_in[12];
  float* out = (float*)d_out;

  // workspace layout (~53 MB)
  float4* csr_w     = (float4*)d_ws;                          // E float4 (12.8 MB)
  ushort* feat      = (ushort*)(csr_w + N_EDGES);             // N*192 bf16 (19.2 MB)
  ushort* h_d3      = feat + (size_t)N_NODES * FEAT;          // 3*N*64 bf16 (19.2 MB)
  float* el         = (float*)(h_d3 + (size_t)HEADS * N_NODES * HID);
  float* er         = el + (size_t)N_NODES * 4;               // N*4
  // --- zeroed region: pooled_sum, deg (contiguous, one memset) ---
  float* pooled_sum = er + (size_t)N_NODES * 4;               // 16*64
  int* deg          = (int*)(pooled_sum + N_GRAPHS * HID);    // N+1
  // --- end zeroed region ---
  int* offs         = deg + (N_NODES + 1);                    // N+1
  int* cursor       = offs + (N_NODES + 1);                   // N
  int* bsum         = cursor + N_NODES;                       // 49
  int* boff         = bsum + SCAN_NB;                         // 49

  size_t zero_bytes = N_GRAPHS * HID * sizeof(float) + (N_NODES + 1) * sizeof(int);
  hipMemsetAsync(pooled_sum, 0, zero_bytes, stream);

  k0_mfma<<<(N_NODES + 63) / 64, 256, 0, stream>>>(h, fc_w, attn_l, attn_r, feat, el, er);
  k1_hist<<<N_EDGES / 256, 256, 0, stream>>>(dst, deg);
  k2a_blocksum<<<SCAN_NB, SCAN_T, 0, stream>>>(deg, bsum);
  k2b_scanb<<<1, 64, 0, stream>>>(bsum, boff, offs);
  k2c_apply<<<SCAN_NB, SCAN_T, 0, stream>>>(deg, boff, offs, cursor);
  k3_edge<<<N_EDGES / 256, 256, 0, stream>>>(src, dst, el, er, cursor, csr_w);
  k4_agg<<<(3 * N_NODES) / 4, 256, 0, stream>>>(offs, csr_w, feat, bias, h_d3);
  k5a_partial<<<(N_NODES + K5_NPB - 1) / K5_NPB, 256, 0, stream>>>(gid, h_d3, pooled_sum);
  k6_final<<<1, 256, 0, stream>>>(gid, pooled_sum, z, lin1_w, lin1_b, lin2_w, lin2_b, out);
}

// Round 7
// 289.142 us; speedup vs baseline: 1.7970x; 1.0926x over previous
//
#include <hip/hip_runtime.h>
#include <math.h>

#define N_NODES 50000
#define N_EDGES 800000
#define N_GRAPHS 16
#define NODE_F 128
#define HID 64
#define OUT_F 128
#define HEADS 3
#define NEG 0.2f
#define FEAT (HEADS*HID)  // 192

typedef float f32x4 __attribute__((ext_vector_type(4)));
typedef short bf16x8 __attribute__((ext_vector_type(8)));

__device__ __forceinline__ ushort f2bf(float x) {
  union { float f; unsigned u; } v; v.f = x;
  unsigned r = v.u + 0x7fff + ((v.u >> 16) & 1);  // round-to-nearest-even
  return (ushort)(r >> 16);
}
__device__ __forceinline__ float bf2f(ushort x) {
  union { unsigned u; float f; } v; v.u = ((unsigned)x) << 16;
  return v.f;
}

// ---------------- K0: feat = h @ fc_w.T via MFMA bf16; el/er in epilogue ----------------
__global__ __launch_bounds__(256) void k0_mfma(
    const float* __restrict__ h, const float* __restrict__ fc_w,
    const float* __restrict__ attn_l, const float* __restrict__ attn_r,
    ushort* __restrict__ feat, float* __restrict__ el, float* __restrict__ er)
{
  __shared__ ushort A[64][136];   // bf16, 272 B row stride
  __shared__ ushort Bs[192][40];  // bf16 K-slice, 80 B row stride
  const int tid = threadIdx.x;
  const int n0 = blockIdx.x * 64;

  for (int i = tid; i < 64 * 32; i += 256) {
    int r = i >> 5, c4 = i & 31;
    if (n0 + r < N_NODES) {
      float4 v = *(const float4*)(h + (size_t)(n0 + r) * NODE_F + c4 * 4);
      unsigned lo = f2bf(v.x) | ((unsigned)f2bf(v.y) << 16);
      unsigned hi = f2bf(v.z) | ((unsigned)f2bf(v.w) << 16);
      *(uint2*)&A[r][c4 * 4] = make_uint2(lo, hi);
    }
  }

  const int lane = tid & 63, wv = tid >> 6;
  const int m = lane & 15, kq = lane >> 4;

  f32x4 acc[12];
#pragma unroll
  for (int t = 0; t < 12; t++) acc[t] = (f32x4){0.f, 0.f, 0.f, 0.f};

  for (int kk = 0; kk < 4; kk++) {
    __syncthreads();
    for (int i = tid; i < 192 * 8; i += 256) {
      int r = i >> 3, c4 = i & 7;
      float4 v = *(const float4*)(fc_w + (size_t)r * NODE_F + kk * 32 + c4 * 4);
      unsigned lo = f2bf(v.x) | ((unsigned)f2bf(v.y) << 16);
      unsigned hi = f2bf(v.z) | ((unsigned)f2bf(v.w) << 16);
      *(uint2*)&Bs[r][c4 * 4] = make_uint2(lo, hi);
    }
    __syncthreads();
    bf16x8 af = *(const bf16x8*)&A[wv * 16 + m][kk * 32 + kq * 8];
#pragma unroll
    for (int t = 0; t < 12; t++) {
      bf16x8 bf = *(const bf16x8*)&Bs[t * 16 + m][kq * 8];
      acc[t] = __builtin_amdgcn_mfma_f32_16x16x32_bf16(af, bf, acc[t], 0, 0, 0);
    }
  }

  const int rbase = n0 + wv * 16 + kq * 4;
#pragma unroll
  for (int t = 0; t < 12; t++) {
#pragma unroll
    for (int reg = 0; reg < 4; reg++) {
      int n = rbase + reg;
      if (n < N_NODES) feat[(size_t)n * FEAT + t * 16 + m] = f2bf(acc[t][reg]);
    }
  }

#pragma unroll
  for (int hh = 0; hh < HEADS; hh++) {
    float elv[4] = {0.f, 0.f, 0.f, 0.f};
    float erv[4] = {0.f, 0.f, 0.f, 0.f};
#pragma unroll
    for (int tt = 0; tt < 4; tt++) {
      int t = hh * 4 + tt;
      float al = attn_l[hh * HID + tt * 16 + m];
      float ar = attn_r[hh * HID + tt * 16 + m];
#pragma unroll
      for (int reg = 0; reg < 4; reg++) {
        elv[reg] = fmaf(acc[t][reg], al, elv[reg]);
        erv[reg] = fmaf(acc[t][reg], ar, erv[reg]);
      }
    }
#pragma unroll
    for (int reg = 0; reg < 4; reg++) {
#pragma unroll
      for (int off = 1; off < 16; off <<= 1) {
        elv[reg] += __shfl_xor(elv[reg], off, 64);
        erv[reg] += __shfl_xor(erv[reg], off, 64);
      }
      int n = rbase + reg;
      if (m == 0 && n < N_NODES) {
        el[(size_t)n * 4 + hh] = elv[reg];
        er[(size_t)n * 4 + hh] = erv[reg];
      }
    }
  }
}

// ---------------- K1: in-degree histogram (int atomics — proven cheap) ----------------
__global__ void k1_hist(const int* __restrict__ dst, int* __restrict__ deg) {
  int e = blockIdx.x * 256 + threadIdx.x;
  atomicAdd(&deg[dst[e]], 1);
}

// ---------------- K2: coalesced 3-stage exclusive scan ----------------
#define SCAN_T 1024
#define SCAN_NB 49  // ceil(50000/1024)

__global__ __launch_bounds__(SCAN_T) void k2a_blocksum(
    const int* __restrict__ deg, int* __restrict__ bsum)
{
  const int tid = threadIdx.x;
  int idx = blockIdx.x * SCAN_T + tid;
  int v = (idx < N_NODES) ? deg[idx] : 0;
#pragma unroll
  for (int off = 32; off; off >>= 1) v += __shfl_xor(v, off, 64);
  __shared__ int ws_[16];
  if ((tid & 63) == 0) ws_[tid >> 6] = v;
  __syncthreads();
  if (tid == 0) {
    int s = 0;
    for (int i = 0; i < 16; i++) s += ws_[i];
    bsum[blockIdx.x] = s;
  }
}

__global__ __launch_bounds__(64) void k2b_scanb(
    const int* __restrict__ bsum, int* __restrict__ boff, int* __restrict__ offs)
{
  const int lane = threadIdx.x;
  int v = (lane < SCAN_NB) ? bsum[lane] : 0;
  int s = v;
#pragma unroll
  for (int off = 1; off < 64; off <<= 1) {
    int t = __shfl_up(s, off, 64);
    if (lane >= off) s += t;
  }
  if (lane < SCAN_NB) boff[lane] = s - v;
  if (lane == SCAN_NB - 1) offs[N_NODES] = s;
}

__global__ __launch_bounds__(SCAN_T) void k2c_apply(
    const int* __restrict__ deg, const int* __restrict__ boff,
    int* __restrict__ offs, int* __restrict__ cursor)
{
  __shared__ int lds[SCAN_T];
  const int tid = threadIdx.x;
  const int idx = blockIdx.x * SCAN_T + tid;
  int v = (idx < N_NODES) ? deg[idx] : 0;
  int s = v;
  lds[tid] = s;
  __syncthreads();
  for (int off = 1; off < SCAN_T; off <<= 1) {
    int t = (tid >= off) ? lds[tid - off] : 0;
    __syncthreads();
    s += t;
    lds[tid] = s;
    __syncthreads();
  }
  int excl = s - v + boff[blockIdx.x];
  if (idx < N_NODES) {
    offs[idx] = excl;
    cursor[idx] = excl;
  }
}

// ---------------- K3: fused edge-weight compute + scatter {w0,w1,w2,byteoff} into CSR ----------------
__global__ __launch_bounds__(256) void k3_edge(
    const int* __restrict__ src, const int* __restrict__ dst,
    const float* __restrict__ el4, const float* __restrict__ er4,
    int* __restrict__ cursor, float4* __restrict__ csr_w)
{
  int e = blockIdx.x * 256 + threadIdx.x;  // grid exact E/256
  int s = src[e], d = dst[e];
  int pos = atomicAdd(&cursor[d], 1);
  float4 elv = ((const float4*)el4)[s];
  float4 erv = ((const float4*)er4)[d];
  float e0 = elv.x + erv.x; e0 = e0 > 0.f ? e0 : NEG * e0;
  float e1 = elv.y + erv.y; e1 = e1 > 0.f ? e1 : NEG * e1;
  float e2 = elv.z + erv.z; e2 = e2 > 0.f ? e2 : NEG * e2;
  float4 r;
  r.x = __expf(e0); r.y = __expf(e1); r.z = __expf(e2);
  r.w = __int_as_float(s * (FEAT * 2));  // byte offset of feat row
  csr_w[pos] = r;
}

// ---------------- K4: wave per node, all heads, single sweep ----------------
// LDS record broadcast (no shuffles); lanes 0-31 take even edges, 32-63 odd;
// each lane owns dim-pair (2d, 2d+1) per head (ushort2 loads, coalesced).
__global__ __launch_bounds__(256) void k4_agg(
    const int* __restrict__ offs, const float4* __restrict__ csr_w,
    const ushort* __restrict__ feat, const float* __restrict__ bias,
    float* __restrict__ h_d)
{
  __shared__ float4 rec[4][64];  // per-wave staging, 4 KB/block
  const int wv = threadIdx.x >> 6, lane = threadIdx.x & 63;
  const int n = blockIdx.x * 4 + wv;  // grid exact: N/4
  const int lo = offs[n], hi = offs[n + 1];
  const int half = lane >> 5;
  const int d = lane & 31;
  const char* fb = (const char*)feat;

  float a0x = 0.f, a0y = 0.f, a1x = 0.f, a1y = 0.f, a2x = 0.f, a2y = 0.f;
  float s0 = 0.f, s1 = 0.f, s2 = 0.f;

  for (int base = lo; base < hi; base += 64) {
    const int cnt = min(64, hi - base);
    if (lane < cnt) {
      float4 c = csr_w[base + lane];
      rec[wv][lane] = c;
      s0 += c.x; s1 += c.y; s2 += c.z;  // each edge counted once (by its staging lane)
    }
    for (int j = half; j < cnt; j += 2) {   // interleaved halves stay balanced
      float4 c = rec[wv][j];                // ds_read_b128 broadcast (2 addrs/wave = free)
      const char* rp = fb + __float_as_int(c.w) + 4 * d;
      ushort2 f0 = *(const ushort2*)(rp);
      ushort2 f1 = *(const ushort2*)(rp + 2 * HID);
      ushort2 f2 = *(const ushort2*)(rp + 4 * HID);
      a0x = fmaf(c.x, bf2f(f0.x), a0x); a0y = fmaf(c.x, bf2f(f0.y), a0y);
      a1x = fmaf(c.y, bf2f(f1.x), a1x); a1y = fmaf(c.y, bf2f(f1.y), a1y);
      a2x = fmaf(c.z, bf2f(f2.x), a2x); a2y = fmaf(c.z, bf2f(f2.y), a2y);
    }
  }
  // combine the two half-wave edge partitions (same dims, disjoint edges)
  a0x += __shfl_xor(a0x, 32, 64); a0y += __shfl_xor(a0y, 32, 64);
  a1x += __shfl_xor(a1x, 32, 64); a1y += __shfl_xor(a1y, 32, 64);
  a2x += __shfl_xor(a2x, 32, 64); a2y += __shfl_xor(a2y, 32, 64);
#pragma unroll
  for (int off = 32; off; off >>= 1) {
    s0 += __shfl_xor(s0, off, 64);
    s1 += __shfl_xor(s1, off, 64);
    s2 += __shfl_xor(s2, off, 64);
  }
  const float i0 = s0 > 0.f ? 1.f / s0 : 0.f;
  const float i1 = s1 > 0.f ? 1.f / s1 : 0.f;
  const float i2 = s2 > 0.f ? 1.f / s2 : 0.f;
  if (half == 0) {
    float2 b0 = *(const float2*)(bias + 2 * d);
    float2 b1 = *(const float2*)(bias + HID + 2 * d);
    float2 b2 = *(const float2*)(bias + 2 * HID + 2 * d);
    float2 o;
    o.x = (fmaf(a0x, i0, b0.x) + fmaf(a1x, i1, b1.x) + fmaf(a2x, i2, b2.x)) * (1.f / 3.f);
    o.y = (fmaf(a0y, i0, b0.y) + fmaf(a1y, i1, b1.y) + fmaf(a2y, i2, b2.y)) * (1.f / 3.f);
    *(float2*)(h_d + (size_t)n * HID + 2 * d) = o;
  }
}

// ---------------- K5: per-graph SUM pooling, grid-stride partials ----------------
#define K5_NPB 128
__global__ __launch_bounds__(256) void k5a_partial(
    const int* __restrict__ graph_id, const float* __restrict__ h_d,
    float* __restrict__ pooled_sum)
{
  const int wave = threadIdx.x >> 6, lane = threadIdx.x & 63;
  const int n0 = blockIdx.x * K5_NPB;
  const int n1 = min(n0 + K5_NPB, N_NODES);
  float acc = 0.f;
  int cur_g = -1;
  for (int i = n0 + wave; i < n1; i += 4) {
    int g = graph_id[i];
    if (g != cur_g) {
      if (cur_g >= 0) atomicAdd(&pooled_sum[cur_g * HID + lane], acc);
      acc = 0.f; cur_g = g;
    }
    acc += h_d[(size_t)i * HID + lane];
  }
  if (cur_g >= 0) atomicAdd(&pooled_sum[cur_g * HID + lane], acc);
}

// ---------------- K6: counts + mean, z @ lin1.T, concat, lin2, sigmoid ----------------
__global__ __launch_bounds__(256) void k6_final(
    const int* __restrict__ graph_id, const float* __restrict__ pooled_sum,
    const float* __restrict__ z,
    const float* __restrict__ lin1_w, const float* __restrict__ lin1_b,
    const float* __restrict__ lin2_w, const float* __restrict__ lin2_b,
    float* __restrict__ out)
{
  __shared__ float cat[N_GRAPHS][2 * HID];
  __shared__ float inv_cnt[N_GRAPHS];
  const int tid = threadIdx.x;
  if (tid < N_GRAPHS) {
    int g = tid;
    int lo, hi;
    { int l = 0, r = N_NODES; while (l < r) { int m = (l + r) >> 1; if (graph_id[m] < g) l = m + 1; else r = m; } lo = l; }
    { int l = 0, r = N_NODES; while (l < r) { int m = (l + r) >> 1; if (graph_id[m] < g + 1) l = m + 1; else r = m; } hi = l; }
    int cnt = hi - lo;
    inv_cnt[g] = 1.f / (float)(cnt > 0 ? cnt : 1);
  }
  __syncthreads();
  for (int i = tid; i < N_GRAPHS * HID; i += 256) {
    cat[i >> 6][i & 63] = pooled_sum[i] * inv_cnt[i >> 6];
  }
  for (int i = tid; i < N_GRAPHS * HID; i += 256) {
    int g = i >> 6, j = i & 63;
    float s = lin1_b[j];
    const float* zr = z + g * OUT_F;
    const float* wr = lin1_w + j * OUT_F;
    for (int k = 0; k < OUT_F; k += 4) {
      float4 zv = *(const float4*)(zr + k);
      float4 wv = *(const float4*)(wr + k);
      s = fmaf(zv.x, wv.x, fmaf(zv.y, wv.y, fmaf(zv.z, wv.z, fmaf(zv.w, wv.w, s))));
    }
    cat[g][HID + j] = s;
  }
  __syncthreads();
  if (tid < N_GRAPHS) {
    float s = lin2_b[0];
    for (int i = 0; i < 2 * HID; i++) s += cat[tid][i] * lin2_w[i];
    out[tid] = 1.f / (1.f + __expf(-s));
  }
}

extern "C" void kernel_launch(void* const* d_in, const int* in_sizes, int n_in,
                              void* d_out, int out_size, void* d_ws, size_t ws_size,
                              hipStream_t stream) {
  (void)in_sizes; (void)n_in; (void)out_size; (void)ws_size;
  const float* h      = (const float*)d_in[0];
  const float* z      = (const float*)d_in[1];
  const int*   src    = (const int*)d_in[2];
  const int*   dst    = (const int*)d_in[3];
  const int*   gid    = (const int*)d_in[4];
  const float* fc_w   = (const float*)d_in[5];
  const float* attn_l = (const float*)d_in[6];
  const float* attn_r = (const float*)d_in[7];
  const float* bias   = (const float*)d_in[8];
  const float* lin1_w = (const float*)d_in[9];
  const float* lin1_b = (const float*)d_in[10];
  const float* lin2_w = (const float*)d_in[11];
  const float* lin2_b = (const float*)d_in[12];
  float* out = (float*)d_out;

  // workspace layout (~48 MB)
  float4* csr_w     = (float4*)d_ws;                          // E float4 (12.8 MB)
  ushort* feat      = (ushort*)(csr_w + N_EDGES);             // N*192 bf16 (19.2 MB)
  float* h_d        = (float*)(feat + (size_t)N_NODES * FEAT);// N*64 fp32 (12.8 MB)
  float* el         = h_d + (size_t)N_NODES * HID;            // N*4
  float* er         = el + (size_t)N_NODES * 4;               // N*4
  // --- zeroed region: pooled_sum, deg (contiguous, one memset) ---
  float* pooled_sum = er + (size_t)N_NODES * 4;               // 16*64
  int* deg          = (int*)(pooled_sum + N_GRAPHS * HID);    // N+1
  // --- end zeroed region ---
  int* offs         = deg + (N_NODES + 1);                    // N+1
  int* cursor       = offs + (N_NODES + 1);                   // N
  int* bsum         = cursor + N_NODES;                       // 49
  int* boff         = bsum + SCAN_NB;                         // 49

  size_t zero_bytes = N_GRAPHS * HID * sizeof(float) + (N_NODES + 1) * sizeof(int);
  hipMemsetAsync(pooled_sum, 0, zero_bytes, stream);

  k0_mfma<<<(N_NODES + 63) / 64, 256, 0, stream>>>(h, fc_w, attn_l, attn_r, feat, el, er);
  k1_hist<<<N_EDGES / 256, 256, 0, stream>>>(dst, deg);
  k2a_blocksum<<<SCAN_NB, SCAN_T, 0, stream>>>(deg, bsum);
  k2b_scanb<<<1, 64, 0, stream>>>(bsum, boff, offs);
  k2c_apply<<<SCAN_NB, SCAN_T, 0, stream>>>(deg, boff, offs, cursor);
  k3_edge<<<N_EDGES / 256, 256, 0, stream>>>(src, dst, el, er, cursor, csr_w);
  k4_agg<<<N_NODES / 4, 256, 0, stream>>>(offs, csr_w, feat, bias, h_d);
  k5a_partial<<<(N_NODES + K5_NPB - 1) / K5_NPB, 256, 0, stream>>>(gid, h_d, pooled_sum);
  k6_final<<<1, 256, 0, stream>>>(gid, pooled_sum, z, lin1_w, lin1_b, lin2_w, lin2_b, out);
}

// Round 8
// 255.286 us; speedup vs baseline: 2.0354x; 1.1326x over previous
//
#include <hip/hip_runtime.h>
#include <math.h>

#define N_NODES 50000
#define N_EDGES 800000
#define N_GRAPHS 16
#define NODE_F 128
#define HID 64
#define OUT_F 128
#define HEADS 3
#define NEG 0.2f
#define FEAT (HEADS*HID)  // 192

typedef float f32x4 __attribute__((ext_vector_type(4)));
typedef float f32x2 __attribute__((ext_vector_type(2)));
typedef short bf16x8 __attribute__((ext_vector_type(8)));

#if defined(__has_builtin)
#if __has_builtin(__builtin_amdgcn_cvt_pk_f32_fp8) && __has_builtin(__builtin_amdgcn_cvt_pk_fp8_f32)
#define USE_FP8 1
#endif
#endif
#ifndef USE_FP8
#define USE_FP8 0
#endif

#if USE_FP8
#define FB 1  // bytes per stored feat element
#else
#define FB 2
#endif

__device__ __forceinline__ ushort f2bf(float x) {
  union { float f; unsigned u; } v; v.f = x;
  unsigned r = v.u + 0x7fff + ((v.u >> 16) & 1);  // round-to-nearest-even
  return (ushort)(r >> 16);
}
__device__ __forceinline__ float bf2f(ushort x) {
  union { unsigned u; float f; } v; v.u = ((unsigned)x) << 16;
  return v.f;
}

__device__ __forceinline__ void feat_store(unsigned char* base, size_t idx, float v) {
#if USE_FP8
  base[idx] = (unsigned char)(__builtin_amdgcn_cvt_pk_fp8_f32(v, 0.f, 0, false) & 0xff);
#else
  ((ushort*)base)[idx] = f2bf(v);
#endif
}

// decode 2 consecutive stored feat elements at byte pointer p
__device__ __forceinline__ f32x2 feat_load2(const char* p) {
#if USE_FP8
  uchar2 u = *(const uchar2*)p;
  unsigned packed = (unsigned)u.x | ((unsigned)u.y << 8);
  return __builtin_amdgcn_cvt_pk_f32_fp8(packed, false);
#else
  ushort2 u = *(const ushort2*)p;
  f32x2 r; r.x = bf2f(u.x); r.y = bf2f(u.y);
  return r;
#endif
}

// ---------------- K0: feat = h @ fc_w.T via MFMA bf16; el/er in epilogue ----------------
__global__ __launch_bounds__(256) void k0_mfma(
    const float* __restrict__ h, const float* __restrict__ fc_w,
    const float* __restrict__ attn_l, const float* __restrict__ attn_r,
    unsigned char* __restrict__ feat, float* __restrict__ el, float* __restrict__ er)
{
  __shared__ ushort A[64][136];   // bf16, 272 B row stride
  __shared__ ushort Bs[192][40];  // bf16 K-slice, 80 B row stride
  const int tid = threadIdx.x;
  const int n0 = blockIdx.x * 64;

  for (int i = tid; i < 64 * 32; i += 256) {
    int r = i >> 5, c4 = i & 31;
    if (n0 + r < N_NODES) {
      float4 v = *(const float4*)(h + (size_t)(n0 + r) * NODE_F + c4 * 4);
      unsigned lo = f2bf(v.x) | ((unsigned)f2bf(v.y) << 16);
      unsigned hi = f2bf(v.z) | ((unsigned)f2bf(v.w) << 16);
      *(uint2*)&A[r][c4 * 4] = make_uint2(lo, hi);
    }
  }

  const int lane = tid & 63, wv = tid >> 6;
  const int m = lane & 15, kq = lane >> 4;

  f32x4 acc[12];
#pragma unroll
  for (int t = 0; t < 12; t++) acc[t] = (f32x4){0.f, 0.f, 0.f, 0.f};

  for (int kk = 0; kk < 4; kk++) {
    __syncthreads();
    for (int i = tid; i < 192 * 8; i += 256) {
      int r = i >> 3, c4 = i & 7;
      float4 v = *(const float4*)(fc_w + (size_t)r * NODE_F + kk * 32 + c4 * 4);
      unsigned lo = f2bf(v.x) | ((unsigned)f2bf(v.y) << 16);
      unsigned hi = f2bf(v.z) | ((unsigned)f2bf(v.w) << 16);
      *(uint2*)&Bs[r][c4 * 4] = make_uint2(lo, hi);
    }
    __syncthreads();
    bf16x8 af = *(const bf16x8*)&A[wv * 16 + m][kk * 32 + kq * 8];
#pragma unroll
    for (int t = 0; t < 12; t++) {
      bf16x8 bf = *(const bf16x8*)&Bs[t * 16 + m][kq * 8];
      acc[t] = __builtin_amdgcn_mfma_f32_16x16x32_bf16(af, bf, acc[t], 0, 0, 0);
    }
  }

  const int rbase = n0 + wv * 16 + kq * 4;
#pragma unroll
  for (int t = 0; t < 12; t++) {
#pragma unroll
    for (int reg = 0; reg < 4; reg++) {
      int n = rbase + reg;
      if (n < N_NODES) feat_store(feat, (size_t)n * FEAT + t * 16 + m, acc[t][reg]);
    }
  }

#pragma unroll
  for (int hh = 0; hh < HEADS; hh++) {
    float elv[4] = {0.f, 0.f, 0.f, 0.f};
    float erv[4] = {0.f, 0.f, 0.f, 0.f};
#pragma unroll
    for (int tt = 0; tt < 4; tt++) {
      int t = hh * 4 + tt;
      float al = attn_l[hh * HID + tt * 16 + m];
      float ar = attn_r[hh * HID + tt * 16 + m];
#pragma unroll
      for (int reg = 0; reg < 4; reg++) {
        elv[reg] = fmaf(acc[t][reg], al, elv[reg]);
        erv[reg] = fmaf(acc[t][reg], ar, erv[reg]);
      }
    }
#pragma unroll
    for (int reg = 0; reg < 4; reg++) {
#pragma unroll
      for (int off = 1; off < 16; off <<= 1) {
        elv[reg] += __shfl_xor(elv[reg], off, 64);
        erv[reg] += __shfl_xor(erv[reg], off, 64);
      }
      int n = rbase + reg;
      if (m == 0 && n < N_NODES) {
        el[(size_t)n * 4 + hh] = elv[reg];
        er[(size_t)n * 4 + hh] = erv[reg];
      }
    }
  }
}

// ---------------- K1: in-degree histogram; atomic return value IS the CSR rank ----------------
__global__ void k1_hist(const int* __restrict__ dst, int* __restrict__ deg,
                        int* __restrict__ rank) {
  int e = blockIdx.x * 256 + threadIdx.x;
  rank[e] = atomicAdd(&deg[dst[e]], 1);
}

// ---------------- K2: coalesced 3-stage exclusive scan ----------------
#define SCAN_T 1024
#define SCAN_NB 49  // ceil(50000/1024)

__global__ __launch_bounds__(SCAN_T) void k2a_blocksum(
    const int* __restrict__ deg, int* __restrict__ bsum)
{
  const int tid = threadIdx.x;
  int idx = blockIdx.x * SCAN_T + tid;
  int v = (idx < N_NODES) ? deg[idx] : 0;
#pragma unroll
  for (int off = 32; off; off >>= 1) v += __shfl_xor(v, off, 64);
  __shared__ int ws_[16];
  if ((tid & 63) == 0) ws_[tid >> 6] = v;
  __syncthreads();
  if (tid == 0) {
    int s = 0;
    for (int i = 0; i < 16; i++) s += ws_[i];
    bsum[blockIdx.x] = s;
  }
}

__global__ __launch_bounds__(64) void k2b_scanb(
    const int* __restrict__ bsum, int* __restrict__ boff, int* __restrict__ offs)
{
  const int lane = threadIdx.x;
  int v = (lane < SCAN_NB) ? bsum[lane] : 0;
  int s = v;
#pragma unroll
  for (int off = 1; off < 64; off <<= 1) {
    int t = __shfl_up(s, off, 64);
    if (lane >= off) s += t;
  }
  if (lane < SCAN_NB) boff[lane] = s - v;
  if (lane == SCAN_NB - 1) offs[N_NODES] = s;
}

// wave-shfl scan: 2 barriers instead of 20
__global__ __launch_bounds__(SCAN_T) void k2c_apply(
    const int* __restrict__ deg, const int* __restrict__ boff,
    int* __restrict__ offs)
{
  __shared__ int wsum[16], woff[16];
  const int tid = threadIdx.x;
  const int lane = tid & 63, wv = tid >> 6;
  const int idx = blockIdx.x * SCAN_T + tid;
  int v = (idx < N_NODES) ? deg[idx] : 0;
  int s = v;
#pragma unroll
  for (int off = 1; off < 64; off <<= 1) {
    int t = __shfl_up(s, off, 64);
    if (lane >= off) s += t;
  }
  if (lane == 63) wsum[wv] = s;
  __syncthreads();
  if (tid < 16) {
    int w = wsum[tid];
    int sc = w;
#pragma unroll
    for (int off = 1; off < 16; off <<= 1) {
      int t = __shfl_up(sc, off, 64);
      if (tid >= off) sc += t;
    }
    woff[tid] = sc - w;
  }
  __syncthreads();
  int excl = s - v + woff[wv] + boff[blockIdx.x];
  if (idx < N_NODES) offs[idx] = excl;
}

// ---------------- K3: edge weights + NO-ATOMIC scatter {w0,w1,w2,byteoff} into CSR ----------------
__global__ __launch_bounds__(256) void k3_edge(
    const int* __restrict__ src, const int* __restrict__ dst,
    const float* __restrict__ el4, const float* __restrict__ er4,
    const int* __restrict__ offs, const int* __restrict__ rank,
    float4* __restrict__ csr_w)
{
  int e = blockIdx.x * 256 + threadIdx.x;  // grid exact E/256
  int s = src[e], d = dst[e];
  int pos = offs[d] + rank[e];
  float4 elv = ((const float4*)el4)[s];
  float4 erv = ((const float4*)er4)[d];
  float e0 = elv.x + erv.x; e0 = e0 > 0.f ? e0 : NEG * e0;
  float e1 = elv.y + erv.y; e1 = e1 > 0.f ? e1 : NEG * e1;
  float e2 = elv.z + erv.z; e2 = e2 > 0.f ? e2 : NEG * e2;
  float4 r;
  r.x = __expf(e0); r.y = __expf(e1); r.z = __expf(e2);
  r.w = __int_as_float(s * (FEAT * FB));  // byte offset of feat row
  csr_w[pos] = r;
}

// ---------------- K4: wave per node, all heads, single sweep ----------------
__global__ __launch_bounds__(256) void k4_agg(
    const int* __restrict__ offs, const float4* __restrict__ csr_w,
    const unsigned char* __restrict__ feat, const float* __restrict__ bias,
    float* __restrict__ h_d)
{
  __shared__ float4 rec[4][64];  // per-wave staging, 4 KB/block
  const int wv = threadIdx.x >> 6, lane = threadIdx.x & 63;
  const int n = blockIdx.x * 4 + wv;  // grid exact: N/4
  const int lo = offs[n], hi = offs[n + 1];
  const int half = lane >> 5;
  const int d = lane & 31;
  const char* fb = (const char*)feat;

  float a0x = 0.f, a0y = 0.f, a1x = 0.f, a1y = 0.f, a2x = 0.f, a2y = 0.f;
  float s0 = 0.f, s1 = 0.f, s2 = 0.f;

  for (int base = lo; base < hi; base += 64) {
    const int cnt = min(64, hi - base);
    if (lane < cnt) {
      float4 c = csr_w[base + lane];
      rec[wv][lane] = c;
      s0 += c.x; s1 += c.y; s2 += c.z;  // each edge counted once (by its staging lane)
    }
    for (int j = half; j < cnt; j += 2) {   // interleaved halves stay balanced
      float4 c = rec[wv][j];                // ds_read broadcast (2 addrs/wave = free)
      const char* rp = fb + __float_as_int(c.w) + 2 * FB * d;
      f32x2 f0 = feat_load2(rp);
      f32x2 f1 = feat_load2(rp + HID * FB);
      f32x2 f2 = feat_load2(rp + 2 * HID * FB);
      a0x = fmaf(c.x, f0.x, a0x); a0y = fmaf(c.x, f0.y, a0y);
      a1x = fmaf(c.y, f1.x, a1x); a1y = fmaf(c.y, f1.y, a1y);
      a2x = fmaf(c.z, f2.x, a2x); a2y = fmaf(c.z, f2.y, a2y);
    }
  }
  // combine the two half-wave edge partitions (same dims, disjoint edges)
  a0x += __shfl_xor(a0x, 32, 64); a0y += __shfl_xor(a0y, 32, 64);
  a1x += __shfl_xor(a1x, 32, 64); a1y += __shfl_xor(a1y, 32, 64);
  a2x += __shfl_xor(a2x, 32, 64); a2y += __shfl_xor(a2y, 32, 64);
#pragma unroll
  for (int off = 32; off; off >>= 1) {
    s0 += __shfl_xor(s0, off, 64);
    s1 += __shfl_xor(s1, off, 64);
    s2 += __shfl_xor(s2, off, 64);
  }
  const float i0 = s0 > 0.f ? 1.f / s0 : 0.f;
  const float i1 = s1 > 0.f ? 1.f / s1 : 0.f;
  const float i2 = s2 > 0.f ? 1.f / s2 : 0.f;
  if (half == 0) {
    float2 b0 = *(const float2*)(bias + 2 * d);
    float2 b1 = *(const float2*)(bias + HID + 2 * d);
    float2 b2 = *(const float2*)(bias + 2 * HID + 2 * d);
    float2 o;
    o.x = (fmaf(a0x, i0, b0.x) + fmaf(a1x, i1, b1.x) + fmaf(a2x, i2, b2.x)) * (1.f / 3.f);
    o.y = (fmaf(a0y, i0, b0.y) + fmaf(a1y, i1, b1.y) + fmaf(a2y, i2, b2.y)) * (1.f / 3.f);
    *(float2*)(h_d + (size_t)n * HID + 2 * d) = o;
  }
}

// ---------------- K5: per-graph SUM pooling, grid-stride partials ----------------
#define K5_NPB 128
__global__ __launch_bounds__(256) void k5a_partial(
    const int* __restrict__ graph_id, const float* __restrict__ h_d,
    float* __restrict__ pooled_sum)
{
  const int wave = threadIdx.x >> 6, lane = threadIdx.x & 63;
  const int n0 = blockIdx.x * K5_NPB;
  const int n1 = min(n0 + K5_NPB, N_NODES);
  float acc = 0.f;
  int cur_g = -1;
  for (int i = n0 + wave; i < n1; i += 4) {
    int g = graph_id[i];
    if (g != cur_g) {
      if (cur_g >= 0) atomicAdd(&pooled_sum[cur_g * HID + lane], acc);
      acc = 0.f; cur_g = g;
    }
    acc += h_d[(size_t)i * HID + lane];
  }
  if (cur_g >= 0) atomicAdd(&pooled_sum[cur_g * HID + lane], acc);
}

// ---------------- K6: counts + mean, z @ lin1.T, concat, lin2, sigmoid ----------------
__global__ __launch_bounds__(256) void k6_final(
    const int* __restrict__ graph_id, const float* __restrict__ pooled_sum,
    const float* __restrict__ z,
    const float* __restrict__ lin1_w, const float* __restrict__ lin1_b,
    const float* __restrict__ lin2_w, const float* __restrict__ lin2_b,
    float* __restrict__ out)
{
  __shared__ float cat[N_GRAPHS][2 * HID];
  __shared__ float inv_cnt[N_GRAPHS];
  const int tid = threadIdx.x;
  if (tid < N_GRAPHS) {
    int g = tid;
    int lo, hi;
    { int l = 0, r = N_NODES; while (l < r) { int m = (l + r) >> 1; if (graph_id[m] < g) l = m + 1; else r = m; } lo = l; }
    { int l = 0, r = N_NODES; while (l < r) { int m = (l + r) >> 1; if (graph_id[m] < g + 1) l = m + 1; else r = m; } hi = l; }
    int cnt = hi - lo;
    inv_cnt[g] = 1.f / (float)(cnt > 0 ? cnt : 1);
  }
  __syncthreads();
  for (int i = tid; i < N_GRAPHS * HID; i += 256) {
    cat[i >> 6][i & 63] = pooled_sum[i] * inv_cnt[i >> 6];
  }
  for (int i = tid; i < N_GRAPHS * HID; i += 256) {
    int g = i >> 6, j = i & 63;
    float s = lin1_b[j];
    const float* zr = z + g * OUT_F;
    const float* wr = lin1_w + j * OUT_F;
    for (int k = 0; k < OUT_F; k += 4) {
      float4 zv = *(const float4*)(zr + k);
      float4 wv = *(const float4*)(wr + k);
      s = fmaf(zv.x, wv.x, fmaf(zv.y, wv.y, fmaf(zv.z, wv.z, fmaf(zv.w, wv.w, s))));
    }
    cat[g][HID + j] = s;
  }
  __syncthreads();
  if (tid < N_GRAPHS) {
    float s = lin2_b[0];
    for (int i = 0; i < 2 * HID; i++) s += cat[tid][i] * lin2_w[i];
    out[tid] = 1.f / (1.f + __expf(-s));
  }
}

extern "C" void kernel_launch(void* const* d_in, const int* in_sizes, int n_in,
                              void* d_out, int out_size, void* d_ws, size_t ws_size,
                              hipStream_t stream) {
  (void)in_sizes; (void)n_in; (void)out_size; (void)ws_size;
  const float* h      = (const float*)d_in[0];
  const float* z      = (const float*)d_in[1];
  const int*   src    = (const int*)d_in[2];
  const int*   dst    = (const int*)d_in[3];
  const int*   gid    = (const int*)d_in[4];
  const float* fc_w   = (const float*)d_in[5];
  const float* attn_l = (const float*)d_in[6];
  const float* attn_r = (const float*)d_in[7];
  const float* bias   = (const float*)d_in[8];
  const float* lin1_w = (const float*)d_in[9];
  const float* lin1_b = (const float*)d_in[10];
  const float* lin2_w = (const float*)d_in[11];
  const float* lin2_b = (const float*)d_in[12];
  float* out = (float*)d_out;

  // workspace layout (~42 MB)
  float4* csr_w     = (float4*)d_ws;                            // E float4 (12.8 MB)
  unsigned char* feat = (unsigned char*)(csr_w + N_EDGES);      // N*192*FB bytes
  float* h_d        = (float*)(feat + (size_t)N_NODES * FEAT * FB); // N*64 fp32
  float* el         = h_d + (size_t)N_NODES * HID;              // N*4
  float* er         = el + (size_t)N_NODES * 4;                 // N*4
  // --- zeroed region: pooled_sum, deg (contiguous, one memset) ---
  float* pooled_sum = er + (size_t)N_NODES * 4;                 // 16*64
  int* deg          = (int*)(pooled_sum + N_GRAPHS * HID);      // N+1
  // --- end zeroed region ---
  int* offs         = deg + (N_NODES + 1);                      // N+1
  int* rank         = offs + (N_NODES + 1);                     // E
  int* bsum         = rank + N_EDGES;                           // 49
  int* boff         = bsum + SCAN_NB;                           // 49

  size_t zero_bytes = N_GRAPHS * HID * sizeof(float) + (N_NODES + 1) * sizeof(int);
  hipMemsetAsync(pooled_sum, 0, zero_bytes, stream);

  k0_mfma<<<(N_NODES + 63) / 64, 256, 0, stream>>>(h, fc_w, attn_l, attn_r, feat, el, er);
  k1_hist<<<N_EDGES / 256, 256, 0, stream>>>(dst, deg, rank);
  k2a_blocksum<<<SCAN_NB, SCAN_T, 0, stream>>>(deg, bsum);
  k2b_scanb<<<1, 64, 0, stream>>>(bsum, boff, offs);
  k2c_apply<<<SCAN_NB, SCAN_T, 0, stream>>>(deg, boff, offs);
  k3_edge<<<N_EDGES / 256, 256, 0, stream>>>(src, dst, el, er, offs, rank, csr_w);
  k4_agg<<<N_NODES / 4, 256, 0, stream>>>(offs, csr_w, feat, bias, h_d);
  k5a_partial<<<(N_NODES + K5_NPB - 1) / K5_NPB, 256, 0, stream>>>(gid, h_d, pooled_sum);
  k6_final<<<1, 256, 0, stream>>>(gid, pooled_sum, z, lin1_w, lin1_b, lin2_w, lin2_b, out);
}